// Round 2
// baseline (474.663 us; speedup 1.0000x reference)
//
#include <hip/hip_runtime.h>

// EdgeBlock: out[e] = relu(concat(edges[e], nodes[send[e]], nodes[recv[e]], gg[batch[e]]) @ W1 + b1) @ W2 + b2
// E=1.6M, in=112 (pad 128), hidden=64, out=32. ALL float tensors are float32; indices int32; out float32.
//
// Strategy: transposed MFMA GEMMs, 16 edges per wave, no LDS.
//   Gather x^T as f32 (coalesced float8 per lane), convert to bf16 in-register (v_perm pack, round-half-up).
//   GEMM1: h^T = W1^T @ x^T (4x MFMA K=128); GEMM2: o^T = W2^T @ h^T, B-frags built via ds_bpermute.
//   Epilogue bias adds in f32; output stored as f32 (16B stores, coalesced).

typedef __attribute__((ext_vector_type(8))) short short8;
typedef __attribute__((ext_vector_type(4))) float floatx4;
typedef __attribute__((ext_vector_type(8))) float floatx8;
typedef __attribute__((ext_vector_type(4))) int intx4;

#define E_TOTAL 1600000
#define NGROUPS (E_TOTAL / 16)   // 100000

// pack two f32 -> (bf16(hi)<<16)|bf16(lo), round-half-up (+0x8000 then take high 16)
__device__ inline unsigned int pack_bf(float lo, float hi) {
    unsigned int a = __builtin_bit_cast(unsigned int, lo) + 0x8000u;
    unsigned int b = __builtin_bit_cast(unsigned int, hi) + 0x8000u;
    return __builtin_amdgcn_perm(b, a, 0x07060302);  // {b.hi16, a.hi16}
}

__device__ inline short8 cvt8(floatx8 f) {
    intx4 r;
    r[0] = (int)pack_bf(f[0], f[1]);
    r[1] = (int)pack_bf(f[2], f[3]);
    r[2] = (int)pack_bf(f[4], f[5]);
    r[3] = (int)pack_bf(f[6], f[7]);
    return __builtin_bit_cast(short8, r);
}

__global__ __launch_bounds__(256) void edge_mlp(
    const float* __restrict__ nodes,   // [50000][32]
    const float* __restrict__ edges,   // [E][32]
    const float* __restrict__ gg,      // [64][16]
    const int* __restrict__ send,
    const int* __restrict__ recv,
    const int* __restrict__ batch,
    const float* __restrict__ W1,      // [112][64]
    const float* __restrict__ b1,      // [64]
    const float* __restrict__ W2,      // [64][32]
    const float* __restrict__ b2,      // [32]
    float* __restrict__ out,           // [E][32]
    int nwaves_total)
{
    const int lane = threadIdx.x & 63;
    const int wid  = (int)((blockIdx.x * blockDim.x + threadIdx.x) >> 6);
    const int q = lane >> 4;     // quad: selects k-block of 8
    const int c = lane & 15;     // A-layout: row m; B-layout: col n; C-layout: col

    // ---- W1^T A-fragments: w1f[s][t], element j: A[m=c][k=q*8+j] of K-step s, hid-tile t
    //      value = W1[s*32+q*8+j][t*16+c], zero-padded for k>=112
    short8 w1f[4][4];
#pragma unroll
    for (int s = 0; s < 4; ++s)
#pragma unroll
        for (int t = 0; t < 4; ++t) {
            floatx8 f;
            const int hid = t * 16 + c;
#pragma unroll
            for (int j = 0; j < 8; ++j) {
                const int k = s * 32 + q * 8 + j;
                f[j] = (k < 112) ? W1[k * 64 + hid] : 0.0f;
            }
            w1f[s][t] = cvt8(f);
        }
    // ---- W2^T A-fragments: w2f[s2][u], element j = W2[s2*32+q*8+j][u*16+c]
    short8 w2f[2][2];
#pragma unroll
    for (int s2 = 0; s2 < 2; ++s2)
#pragma unroll
        for (int u = 0; u < 2; ++u) {
            floatx8 f;
            const int od = u * 16 + c;
#pragma unroll
            for (int j = 0; j < 8; ++j)
                f[j] = W2[(s2 * 32 + q * 8 + j) * 32 + od];
            w2f[s2][u] = cvt8(f);
        }
    // ---- biases (f32, added in epilogue), C-layout row = tile*16 + q*4 + r
    float b1v[4][4], b2v[2][4];
#pragma unroll
    for (int t = 0; t < 4; ++t)
#pragma unroll
        for (int r = 0; r < 4; ++r) b1v[t][r] = b1[t * 16 + q * 4 + r];
#pragma unroll
    for (int u = 0; u < 2; ++u)
#pragma unroll
        for (int r = 0; r < 4; ++r) b2v[u][r] = b2[u * 16 + q * 4 + r];

    // bpermute source-lane byte indices for the C->B quad shuffle (derivation in journal):
    // target (q,c) uint m wants source lane q'*16+c with q' = (q&1)*2 + (m>>1), tile t = 2*s2 + (q>>1)
    const int idx_lo = (((q & 1) * 2) * 16 + c) * 4;  // m = 0,1
    const int idx_hi = idx_lo + 64;                   // m = 2,3
    const bool want_hi_tile = (q >= 2);

    for (int g = wid; g < NGROUPS; g += nwaves_total) {
        const int e = g * 16 + c;
        const int se = send[e];
        const int re = recv[e];
        const int be = batch[e];

        // x^T gather, f32: 32B per lane per segment (k-block q*8..q*8+7 of each 32-k segment)
        floatx8 fx0 = *(const floatx8*)(edges + (size_t)e * 32 + q * 8);      // k 0..31
        floatx8 fx1 = *(const floatx8*)(nodes + (size_t)se * 32 + q * 8);     // k 32..63
        floatx8 fx2 = *(const floatx8*)(nodes + (size_t)re * 32 + q * 8);     // k 64..95
        floatx8 fx3 = {0.f, 0.f, 0.f, 0.f, 0.f, 0.f, 0.f, 0.f};               // k 96..127 pad
        if (q < 2) fx3 = *(const floatx8*)(gg + (size_t)be * 16 + q * 8);

        short8 bx0 = cvt8(fx0), bx1 = cvt8(fx1), bx2 = cvt8(fx2), bx3 = cvt8(fx3);

        // GEMM1: h^T tiles t=0..3 (hidden row t*16+q*4+r, col = edge c)
        floatx4 acc[4];
#pragma unroll
        for (int t = 0; t < 4; ++t) {
            floatx4 a = {0.f, 0.f, 0.f, 0.f};
            a = __builtin_amdgcn_mfma_f32_16x16x32_bf16(w1f[0][t], bx0, a, 0, 0, 0);
            a = __builtin_amdgcn_mfma_f32_16x16x32_bf16(w1f[1][t], bx1, a, 0, 0, 0);
            a = __builtin_amdgcn_mfma_f32_16x16x32_bf16(w1f[2][t], bx2, a, 0, 0, 0);
            a = __builtin_amdgcn_mfma_f32_16x16x32_bf16(w1f[3][t], bx3, a, 0, 0, 0);
            acc[t] = a;
        }

        // bias + relu + pack: pk[t][p] holds hiddens (t*16+q*4+2p, +1) at edge c, bf16 pair
        unsigned int pk[4][2];
#pragma unroll
        for (int t = 0; t < 4; ++t) {
            float v0 = fmaxf(acc[t][0] + b1v[t][0], 0.f);
            float v1 = fmaxf(acc[t][1] + b1v[t][1], 0.f);
            float v2 = fmaxf(acc[t][2] + b1v[t][2], 0.f);
            float v3 = fmaxf(acc[t][3] + b1v[t][3], 0.f);
            pk[t][0] = pack_bf(v0, v1);
            pk[t][1] = pack_bf(v2, v3);
        }

        // GEMM2: o^T = W2^T @ h^T ; build h^T B-frags from pk via ds_bpermute
        floatx4 acc2[2];
        acc2[0] = floatx4{0.f, 0.f, 0.f, 0.f};
        acc2[1] = floatx4{0.f, 0.f, 0.f, 0.f};
#pragma unroll
        for (int s2 = 0; s2 < 2; ++s2) {
            intx4 br;
#pragma unroll
            for (int m = 0; m < 4; ++m) {
                const int idx = (m >= 2) ? idx_hi : idx_lo;
                int vlo = __builtin_amdgcn_ds_bpermute(idx, (int)pk[2 * s2][m & 1]);
                int vhi = __builtin_amdgcn_ds_bpermute(idx, (int)pk[2 * s2 + 1][m & 1]);
                br[m] = want_hi_tile ? vhi : vlo;
            }
            short8 bB = __builtin_bit_cast(short8, br);
            acc2[0] = __builtin_amdgcn_mfma_f32_16x16x32_bf16(w2f[s2][0], bB, acc2[0], 0, 0, 0);
            acc2[1] = __builtin_amdgcn_mfma_f32_16x16x32_bf16(w2f[s2][1], bB, acc2[1], 0, 0, 0);
        }

        // store f32: lane holds out dims u*16+q*4+{0..3} of edge e -> 16B stores
#pragma unroll
        for (int u = 0; u < 2; ++u) {
            floatx4 o;
            o[0] = acc2[u][0] + b2v[u][0];
            o[1] = acc2[u][1] + b2v[u][1];
            o[2] = acc2[u][2] + b2v[u][2];
            o[3] = acc2[u][3] + b2v[u][3];
            *(floatx4*)(out + (size_t)e * 32 + u * 16 + q * 4) = o;
        }
    }
}

extern "C" void kernel_launch(void* const* d_in, const int* in_sizes, int n_in,
                              void* d_out, int out_size, void* d_ws, size_t ws_size,
                              hipStream_t stream) {
    const float* nodes = (const float*)d_in[0];
    const float* edges = (const float*)d_in[1];
    const float* gg    = (const float*)d_in[2];
    const int* send  = (const int*)d_in[3];
    const int* recv  = (const int*)d_in[4];
    const int* batch = (const int*)d_in[5];
    const float* W1 = (const float*)d_in[6];
    const float* b1 = (const float*)d_in[7];
    const float* W2 = (const float*)d_in[8];
    const float* b2 = (const float*)d_in[9];
    float* out = (float*)d_out;

    const int blocks = 2500;                 // 10000 waves -> 10 groups/wave
    const int nwaves = blocks * (256 / 64);
    edge_mlp<<<blocks, 256, 0, stream>>>(nodes, edges, gg, send, recv, batch,
                                         W1, b1, W2, b2, out, nwaves);
}